// Round 3
// baseline (122.051 us; speedup 1.0000x reference)
//
#include <hip/hip_runtime.h>

#define BB 4
#define NN 512
#define FIN 128
#define HH 4
#define DD 32
#define HID 128
#define NOUT 384   // 128 src + 128 tgt + 128 res
#define MT 8
#define ROWS 16
#define LN_EPS 1e-5f
#define NEG 0.2f
#define SCALE 0.17677669529663687f

__device__ __forceinline__ float leaky(float x){ return x > 0.f ? x : NEG*x; }

// Pack Wt[k][o]: o in [0,128)=W_src rows, [128,256)=W_tgt rows, [256,384)=W_res rows
__global__ void pack_w(const float* __restrict__ Wsrc, const float* __restrict__ Wtgt,
                       const float* __restrict__ Wres, float* __restrict__ Wt) {
    int idx = blockIdx.x * 256 + threadIdx.x;
    if (idx >= FIN * NOUT) return;
    int k = idx / NOUT, o = idx % NOUT;
    float v;
    if (o < 128)      v = Wsrc[o * FIN + k];
    else if (o < 256) v = Wtgt[(o - 128) * FIN + k];
    else              v = Wres[(o - 256) * FIN + k];
    Wt[idx] = v;
}

// Fused proj: Linear -> LayerNorm(32) -> LeakyReLU for src/tgt, Linear+bias+Leaky for res
__global__ __launch_bounds__(NOUT) void proj_kernel(
    const float* __restrict__ x, const float* __restrict__ Wt,
    const float* __restrict__ gsrc, const float* __restrict__ bsrc,
    const float* __restrict__ gtgt, const float* __restrict__ btgt,
    const float* __restrict__ bres,
    float* __restrict__ Usrc, float* __restrict__ Utgt, float* __restrict__ res)
{
    __shared__ float xs[MT * FIN];
    int tid = threadIdx.x;
    int r0 = blockIdx.x * MT;              // row over flattened [B*N]
    const float* base = x + (size_t)r0 * FIN;
    for (int idx = tid; idx < MT * FIN; idx += NOUT) xs[idx] = base[idx];
    __syncthreads();

    int o = tid;
    float acc[MT];
    #pragma unroll
    for (int m = 0; m < MT; m++) acc[m] = 0.f;
    for (int k = 0; k < FIN; k++) {
        float w = Wt[k * NOUT + o];
        #pragma unroll
        for (int m = 0; m < MT; m++) acc[m] = fmaf(w, xs[m * FIN + k], acc[m]);
    }

    float gg = 1.f, bb2 = 0.f, bres_v = 0.f;
    if (o < 128)      { gg = gsrc[o];       bb2 = bsrc[o]; }
    else if (o < 256) { gg = gtgt[o - 128]; bb2 = btgt[o - 128]; }
    else              { bres_v = bres[o - 256]; }

    #pragma unroll
    for (int m = 0; m < MT; m++) {
        int r = r0 + m;
        int b = r >> 9;            // /512
        int n = r & (NN - 1);
        float v = acc[m];
        if (o < 256) {
            float s = v, sq = v * v;
            #pragma unroll
            for (int msk = 16; msk >= 1; msk >>= 1) {
                s  += __shfl_xor(s,  msk);
                sq += __shfl_xor(sq, msk);
            }
            float mean = s * (1.f / DD);
            float var  = sq * (1.f / DD) - mean * mean;
            float nv = (v - mean) * rsqrtf(var + LN_EPS);
            nv = leaky(nv * gg + bb2);
            int oo = o & 127;
            int hh = oo >> 5, d = oo & 31;
            float* dst = (o < 128) ? Usrc : Utgt;
            dst[((size_t)(b * HH + hh) * NN + n) * DD + d] = nv;
        } else {
            res[(size_t)r * HID + (o - 256)] = leaky(v + bres_v);
        }
    }
}

// Attention: one block per (b,h,16-row i-tile).
// e-phase pure-VALU (t columns in registers); agg via XOR-swizzled scalar tT reads.
__global__ __launch_bounds__(256, 2) void attn_kernel(
    const float* __restrict__ Usrc, const float* __restrict__ Utgt,
    const float* __restrict__ attn, const float* __restrict__ res,
    float* __restrict__ out)
{
    __shared__ __align__(16) float tT[DD * NN];      // 64KB, phys col = j ^ d
    __shared__ __align__(16) float p4[NN * 4];       // 8KB, [j][r] current 4-row chunk
    __shared__ __align__(16) float s_lds[ROWS][DD];  // 2KB
    __shared__ __align__(16) float part[8][4][DD];   // 4KB
    __shared__ float a_lds[DD];
    __shared__ float wsum[ROWS][4];

    const int tid = threadIdx.x;
    const int blk = blockIdx.x;
    const int it = blk & 31;               // N/ROWS = 32 tiles
    const int h  = (blk >> 5) & 3;
    const int b  = blk >> 7;

    const float* tgt = Utgt + (size_t)(b * HH + h) * NN * DD;
    const float* src = Usrc + (size_t)(b * HH + h) * NN * DD + (size_t)(it * ROWS) * DD;

    const int j0 = tid, j1 = tid + 256;
    float t0r[DD], t1r[DD];
    {
        const float* c0 = tgt + j0 * DD;
        const float* c1 = tgt + j1 * DD;
        #pragma unroll
        for (int q = 0; q < 8; q++) {
            float4 v0 = *(const float4*)(c0 + q * 4);
            float4 v1 = *(const float4*)(c1 + q * 4);
            int d0 = q * 4;
            t0r[d0+0] = v0.x; t0r[d0+1] = v0.y; t0r[d0+2] = v0.z; t0r[d0+3] = v0.w;
            t1r[d0+0] = v1.x; t1r[d0+1] = v1.y; t1r[d0+2] = v1.z; t1r[d0+3] = v1.w;
            tT[(d0+0)*NN + (j0 ^ (d0+0))] = v0.x;
            tT[(d0+1)*NN + (j0 ^ (d0+1))] = v0.y;
            tT[(d0+2)*NN + (j0 ^ (d0+2))] = v0.z;
            tT[(d0+3)*NN + (j0 ^ (d0+3))] = v0.w;
            tT[(d0+0)*NN + (j1 ^ (d0+0))] = v1.x;
            tT[(d0+1)*NN + (j1 ^ (d0+1))] = v1.y;
            tT[(d0+2)*NN + (j1 ^ (d0+2))] = v1.z;
            tT[(d0+3)*NN + (j1 ^ (d0+3))] = v1.w;
        }
    }
    if (tid < 128) {
        int r = tid >> 3, d0 = (tid & 7) << 2;
        *(float4*)&s_lds[r][d0] = *(const float4*)(src + r * DD + d0);
    }
    if (tid < DD) a_lds[tid] = attn[h * DD + tid] * SCALE;
    __syncthreads();

    // At[j] = 0.6 * <a', t_j>  (row term 0.6*<a', s_i> cancels in softmax; no max
    // subtraction needed: |e| <~ 25, fp32 exp is safe and softmax is shift-invariant)
    float At0 = 0.f, At1 = 0.f;
    #pragma unroll
    for (int dg = 0; dg < 8; dg++) {
        float4 a4 = *(float4*)&a_lds[dg * 4];
        At0 = fmaf(a4.x, t0r[dg*4+0], At0); At0 = fmaf(a4.y, t0r[dg*4+1], At0);
        At0 = fmaf(a4.z, t0r[dg*4+2], At0); At0 = fmaf(a4.w, t0r[dg*4+3], At0);
        At1 = fmaf(a4.x, t1r[dg*4+0], At1); At1 = fmaf(a4.y, t1r[dg*4+1], At1);
        At1 = fmaf(a4.z, t1r[dg*4+2], At1); At1 = fmaf(a4.w, t1r[dg*4+3], At1);
    }
    At0 *= 0.6f; At1 *= 0.6f;

    // e~[r][j] = At[j] + 0.4 * sum_d a'_d * |s[r][d] + t[j][d]|   (pure VALU)
    float acc0[ROWS], acc1[ROWS];
    #pragma unroll
    for (int r = 0; r < ROWS; r++) { acc0[r] = 0.f; acc1[r] = 0.f; }

    #pragma unroll
    for (int dg = 0; dg < 8; dg++) {
        float4 a4 = *(float4*)&a_lds[dg * 4];
        float u00 = t0r[dg*4+0], u01 = t0r[dg*4+1], u02 = t0r[dg*4+2], u03 = t0r[dg*4+3];
        float u10 = t1r[dg*4+0], u11 = t1r[dg*4+1], u12 = t1r[dg*4+2], u13 = t1r[dg*4+3];
        #pragma unroll
        for (int r = 0; r < ROWS; r++) {
            float4 sv = *(float4*)&s_lds[r][dg * 4];
            acc0[r] = fmaf(a4.x, fabsf(sv.x + u00), acc0[r]);
            acc0[r] = fmaf(a4.y, fabsf(sv.y + u01), acc0[r]);
            acc0[r] = fmaf(a4.z, fabsf(sv.z + u02), acc0[r]);
            acc0[r] = fmaf(a4.w, fabsf(sv.w + u03), acc0[r]);
            acc1[r] = fmaf(a4.x, fabsf(sv.x + u10), acc1[r]);
            acc1[r] = fmaf(a4.y, fabsf(sv.y + u11), acc1[r]);
            acc1[r] = fmaf(a4.z, fabsf(sv.z + u12), acc1[r]);
            acc1[r] = fmaf(a4.w, fabsf(sv.w + u13), acc1[r]);
        }
    }

    // p = exp(e~), per-row sum via wave butterfly (no max pass)
    const int lane = tid & 63, wid = tid >> 6;
    #pragma unroll
    for (int r = 0; r < ROWS; r++) {
        acc0[r] = __expf(fmaf(0.4f, acc0[r], At0));
        acc1[r] = __expf(fmaf(0.4f, acc1[r], At1));
        float s = acc0[r] + acc1[r];
        #pragma unroll
        for (int msk = 32; msk >= 1; msk >>= 1) s += __shfl_xor(s, msk);
        if (lane == 0) wsum[r][wid] = s;
    }
    // publish p chunk 0 (rows 0..3)
    #pragma unroll
    for (int r = 0; r < 4; r++) { p4[j0 * 4 + r] = acc0[r]; p4[j1 * 4 + r] = acc1[r]; }
    __syncthreads();

    // agg: 8 groups of 32 lanes; group g sweeps j in [g*64, g*64+64), lane owns d.
    // tT scalar reads conflict-free (bank = (j^d)%32 distinct); p4 reads broadcast.
    const int g = tid >> 5, dd2 = tid & 31;
    const int jbase = g * 64;
    const int tbase = dd2 * NN + jbase;
    #pragma unroll
    for (int c = 0; c < 4; c++) {
        float g0 = 0.f, g1 = 0.f, g2 = 0.f, g3 = 0.f;
        #pragma unroll 16
        for (int jj = 0; jj < 64; jj++) {
            float tv = tT[tbase + (jj ^ dd2)];
            float4 pv = *(float4*)&p4[(jbase + jj) * 4];
            g0 = fmaf(tv, pv.x, g0);
            g1 = fmaf(tv, pv.y, g1);
            g2 = fmaf(tv, pv.z, g2);
            g3 = fmaf(tv, pv.w, g3);
        }
        part[g][0][dd2] = g0; part[g][1][dd2] = g1;
        part[g][2][dd2] = g2; part[g][3][dd2] = g3;
        __syncthreads();                         // part ready; p4 chunk consumed
        if (c < 3) {
            #pragma unroll
            for (int r = 0; r < 4; r++) {
                p4[j0 * 4 + r] = acc0[(c + 1) * 4 + r];
                p4[j1 * 4 + r] = acc1[(c + 1) * 4 + r];
            }
        }
        if (tid < 128) {
            int r2 = tid >> 5, d2 = tid & 31;
            float v = 0.f;
            #pragma unroll
            for (int gg = 0; gg < 8; gg++) v += part[gg][r2][d2];
            int r = c * 4 + r2;
            float sum = (wsum[r][0] + wsum[r][1]) + (wsum[r][2] + wsum[r][3]);
            v /= sum;
            int i = it * ROWS + r;
            size_t row = (size_t)b * NN + i;
            float rv = res[row * HID + h * DD + d2];
            out[row * HID + h * DD + d2] = fmaxf(v + rv, 0.f);
        }
        if (c < 3) __syncthreads();              // next p4 ready, part consumed
    }
}

extern "C" void kernel_launch(void* const* d_in, const int* in_sizes, int n_in,
                              void* d_out, int out_size, void* d_ws, size_t ws_size,
                              hipStream_t stream) {
    const float* uf   = (const float*)d_in[0];
    const float* Wsrc = (const float*)d_in[1];
    const float* gsrc = (const float*)d_in[2];
    const float* bsrc = (const float*)d_in[3];
    const float* Wtgt = (const float*)d_in[4];
    const float* gtgt = (const float*)d_in[5];
    const float* btgt = (const float*)d_in[6];
    const float* attn = (const float*)d_in[7];
    const float* Wres = (const float*)d_in[8];
    const float* bres = (const float*)d_in[9];
    float* out = (float*)d_out;

    float* ws   = (float*)d_ws;
    float* Wt   = ws;                       // 128*384   = 49152
    float* Usrc = ws + 49152;               // 4*4*512*32 = 262144
    float* Utgt = Usrc + 262144;
    float* resb = Utgt + 262144;

    pack_w<<<(FIN * NOUT + 255) / 256, 256, 0, stream>>>(Wsrc, Wtgt, Wres, Wt);
    proj_kernel<<<(BB * NN) / MT, NOUT, 0, stream>>>(uf, Wt, gsrc, bsrc, gtgt, btgt,
                                                     bres, Usrc, Utgt, resb);
    attn_kernel<<<BB * HH * (NN / ROWS), 256, 0, stream>>>(Usrc, Utgt, attn, resb, out);
}

// Round 4
// 47.490 us; speedup vs baseline: 2.5700x; 2.5700x over previous
//
#include <hip/hip_runtime.h>

#define BB 4
#define NN 512
#define FIN 128
#define HH 4
#define DD 32
#define HID 128
#define NOUT 384   // 128 src + 128 tgt + 128 res
#define MT 8
#define ROWS 16
#define LN_EPS 1e-5f
#define NEG 0.2f
#define SCALE 0.17677669529663687f

__device__ __forceinline__ float leaky(float x){ return x > 0.f ? x : NEG*x; }

// round-to-nearest-even fp32 -> bf16 (finite inputs)
__device__ __forceinline__ unsigned f2bf(float f){
    unsigned u = __float_as_uint(f);
    return (u + 0x7fffu + ((u >> 16) & 1u)) >> 16;
}

// Pack Wt[k][o]: o in [0,128)=W_src rows, [128,256)=W_tgt rows, [256,384)=W_res rows
__global__ void pack_w(const float* __restrict__ Wsrc, const float* __restrict__ Wtgt,
                       const float* __restrict__ Wres, float* __restrict__ Wt) {
    int idx = blockIdx.x * 256 + threadIdx.x;
    if (idx >= FIN * NOUT) return;
    int k = idx / NOUT, o = idx % NOUT;
    float v;
    if (o < 128)      v = Wsrc[o * FIN + k];
    else if (o < 256) v = Wtgt[(o - 128) * FIN + k];
    else              v = Wres[(o - 256) * FIN + k];
    Wt[idx] = v;
}

// Fused proj: Linear -> LayerNorm(32) -> LeakyReLU for src/tgt, Linear+bias+Leaky for res
__global__ __launch_bounds__(NOUT) void proj_kernel(
    const float* __restrict__ x, const float* __restrict__ Wt,
    const float* __restrict__ gsrc, const float* __restrict__ bsrc,
    const float* __restrict__ gtgt, const float* __restrict__ btgt,
    const float* __restrict__ bres,
    float* __restrict__ Usrc, float* __restrict__ Utgt, float* __restrict__ res)
{
    __shared__ float xs[MT * FIN];
    int tid = threadIdx.x;
    int r0 = blockIdx.x * MT;              // row over flattened [B*N]
    const float* base = x + (size_t)r0 * FIN;
    for (int idx = tid; idx < MT * FIN; idx += NOUT) xs[idx] = base[idx];
    __syncthreads();

    int o = tid;
    float acc[MT];
    #pragma unroll
    for (int m = 0; m < MT; m++) acc[m] = 0.f;
    for (int k = 0; k < FIN; k++) {
        float w = Wt[k * NOUT + o];
        #pragma unroll
        for (int m = 0; m < MT; m++) acc[m] = fmaf(w, xs[m * FIN + k], acc[m]);
    }

    float gg = 1.f, bb2 = 0.f, bres_v = 0.f;
    if (o < 128)      { gg = gsrc[o];       bb2 = bsrc[o]; }
    else if (o < 256) { gg = gtgt[o - 128]; bb2 = btgt[o - 128]; }
    else              { bres_v = bres[o - 256]; }

    #pragma unroll
    for (int m = 0; m < MT; m++) {
        int r = r0 + m;
        int b = r >> 9;            // /512
        int n = r & (NN - 1);
        float v = acc[m];
        if (o < 256) {
            float s = v, sq = v * v;
            #pragma unroll
            for (int msk = 16; msk >= 1; msk >>= 1) {
                s  += __shfl_xor(s,  msk);
                sq += __shfl_xor(sq, msk);
            }
            float mean = s * (1.f / DD);
            float var  = sq * (1.f / DD) - mean * mean;
            float nv = (v - mean) * rsqrtf(var + LN_EPS);
            nv = leaky(nv * gg + bb2);
            int oo = o & 127;
            int hh = oo >> 5, d = oo & 31;
            float* dst = (o < 128) ? Usrc : Utgt;
            dst[((size_t)(b * HH + hh) * NN + n) * DD + d] = nv;
        } else {
            res[(size_t)r * HID + (o - 256)] = leaky(v + bres_v);
        }
    }
}

// Attention: one block per (b,h,16-row i-tile).
// e-phase: t in VGPRs (2 adjacent cols, sequential), s/a via uniform scalar loads -> ZERO LDS.
// agg: t bf16 pairs in LDS (pair-swizzle (j>>1)^d), p fp32 [512][16] (quad-swizzled), one sweep.
__global__ __launch_bounds__(256) void attn_kernel(
    const float* __restrict__ Usrc, const float* __restrict__ Utgt,
    const float* __restrict__ attn, const float* __restrict__ res,
    float* __restrict__ out)
{
    __shared__ unsigned tTb[DD * (NN / 2)];   // 32KB: [d][(j>>1)^d], lo=even j, hi=odd j (bf16)
    __shared__ float pL[NN * 16];             // 32KB: slot s=(j>>1)+(j&1)*256; quad rq at (rq^((s>>1)&3))
    __shared__ float part[8 * DD * 8];        // 8KB : [g][d][8], quad rq at (rq^(d&1))
    __shared__ float wsum[ROWS][4];

    const int tid = threadIdx.x;
    const int blk = blockIdx.x;
    const int it = blk & 31;               // N/ROWS = 32 tiles
    const int h  = (blk >> 5) & 3;
    const int b  = blk >> 7;

    const float* tgt  = Utgt + (size_t)(b * HH + h) * NN * DD;
    const float* srcU = Usrc + (size_t)(b * HH + h) * NN * DD + (size_t)(it * ROWS) * DD; // uniform
    const float* aU   = attn + h * DD;                                                    // uniform

    // ---- stage: 2 adjacent t columns -> regs; pack bf16 pairs -> tTb ----
    float t0r[DD], t1r[DD];
    {
        const float* c = tgt + (size_t)(2 * tid) * DD;
        #pragma unroll
        for (int q = 0; q < 8; q++) {
            float4 v0 = *(const float4*)(c + q * 4);
            float4 v1 = *(const float4*)(c + DD + q * 4);
            int d0 = q * 4;
            t0r[d0+0]=v0.x; t0r[d0+1]=v0.y; t0r[d0+2]=v0.z; t0r[d0+3]=v0.w;
            t1r[d0+0]=v1.x; t1r[d0+1]=v1.y; t1r[d0+2]=v1.z; t1r[d0+3]=v1.w;
            #pragma unroll
            for (int e = 0; e < 4; e++) {
                int d = d0 + e;
                tTb[d * 256 + (tid ^ d)] = f2bf(t0r[d]) | (f2bf(t1r[d]) << 16);
            }
        }
    }

    // ---- e-phase (no LDS): e~ = 0.6*SCALE*<a,t> + 0.4*SCALE*sum_d a_d*|s_rd+t_jd| ----
    float At0 = 0.f, At1 = 0.f;
    float acc0[ROWS], acc1[ROWS];
    #pragma unroll
    for (int r = 0; r < ROWS; r++) { acc0[r] = 0.f; acc1[r] = 0.f; }

    #pragma unroll
    for (int d = 0; d < DD; d++) {         // column 0 (j = 2*tid)
        const float ad = aU[d];            // uniform -> s_load
        const float td = t0r[d];
        At0 = fmaf(ad, td, At0);
        #pragma unroll
        for (int r = 0; r < ROWS; r++)
            acc0[r] = fmaf(ad, fabsf(srcU[r * DD + d] + td), acc0[r]);
    }
    #pragma unroll
    for (int d = 0; d < DD; d++) {         // column 1 (j = 2*tid+1)
        const float ad = aU[d];
        const float td = t1r[d];
        At1 = fmaf(ad, td, At1);
        #pragma unroll
        for (int r = 0; r < ROWS; r++)
            acc1[r] = fmaf(ad, fabsf(srcU[r * DD + d] + td), acc1[r]);
    }

    // ---- p = exp(e~) (softmax shift-invariance: row term dropped, no max pass) ----
    const int lane = tid & 63, wid = tid >> 6;
    const float c0 = 0.6f * SCALE * At0, c1 = 0.6f * SCALE * At1;
    #pragma unroll
    for (int r = 0; r < ROWS; r++) {
        acc0[r] = __expf(fmaf(0.4f * SCALE, acc0[r], c0));
        acc1[r] = __expf(fmaf(0.4f * SCALE, acc1[r], c1));
        float s = acc0[r] + acc1[r];
        #pragma unroll
        for (int msk = 32; msk >= 1; msk >>= 1) s += __shfl_xor(s, msk);
        if (lane == 0) wsum[r][wid] = s;
    }

    // ---- publish p: slot tid (even col) and 256+tid (odd col), quad-swizzled ----
    {
        const int k0 = (tid >> 1) & 3;               // slot tid
        const int k1 = ((256 + tid) >> 1) & 3;       // slot 256+tid
        #pragma unroll
        for (int rq = 0; rq < 4; rq++) {
            *(float4*)&pL[tid * 16 + ((rq ^ k0) << 2)] =
                make_float4(acc0[rq*4], acc0[rq*4+1], acc0[rq*4+2], acc0[rq*4+3]);
            *(float4*)&pL[(256 + tid) * 16 + ((rq ^ k1) << 2)] =
                make_float4(acc1[rq*4], acc1[rq*4+1], acc1[rq*4+2], acc1[rq*4+3]);
        }
    }
    __syncthreads();                                 // B1: tTb + pL + wsum ready

    // ---- agg sweep: group g (32 lanes) covers j in [64g,64g+64); lane owns d ----
    const int g = tid >> 5, d2 = tid & 31;
    const int pb = g << 5;                           // 32 pair-slots per group
    float agg[ROWS];
    #pragma unroll
    for (int r = 0; r < ROWS; r++) agg[r] = 0.f;

    #pragma unroll 8
    for (int q = 0; q < 32; q++) {
        unsigned u = tTb[d2 * 256 + ((pb + q) ^ d2)];
        float fe = __uint_as_float(u << 16);         // even col t (bf16)
        float fo = __uint_as_float(u & 0xffff0000u); // odd col t
        const int se = pb + q, so = se + 256;
        const int k = (se >> 1) & 3;                 // (so>>1)&3 == k as well
        #pragma unroll
        for (int rq = 0; rq < 4; rq++) {
            float4 pe = *(float4*)&pL[se * 16 + ((rq ^ k) << 2)];
            float4 po = *(float4*)&pL[so * 16 + ((rq ^ k) << 2)];
            agg[rq*4+0] = fmaf(fe, pe.x, fmaf(fo, po.x, agg[rq*4+0]));
            agg[rq*4+1] = fmaf(fe, pe.y, fmaf(fo, po.y, agg[rq*4+1]));
            agg[rq*4+2] = fmaf(fe, pe.z, fmaf(fo, po.z, agg[rq*4+2]));
            agg[rq*4+3] = fmaf(fe, pe.w, fmaf(fo, po.w, agg[rq*4+3]));
        }
    }

    // ---- cross-group reduce + epilogue, two 8-row half-passes ----
    #pragma unroll
    for (int hf = 0; hf < 2; hf++) {
        #pragma unroll
        for (int rq = 0; rq < 2; rq++) {
            int f = ((rq ^ (d2 & 1)) << 2);
            *(float4*)&part[g * 256 + d2 * 8 + f] =
                make_float4(agg[hf*8+rq*4], agg[hf*8+rq*4+1], agg[hf*8+rq*4+2], agg[hf*8+rq*4+3]);
        }
        __syncthreads();                             // part half ready
        {
            const int r2 = tid >> 5, dE = tid & 31;  // 8 rows x 32 d = 256 threads
            float v = 0.f;
            const int off = dE * 8 + ((((r2 >> 2) ^ (dE & 1)) << 2)) + (r2 & 3);
            #pragma unroll
            for (int gg = 0; gg < 8; gg++) v += part[gg * 256 + off];
            const int rg = hf * 8 + r2;
            float sum = (wsum[rg][0] + wsum[rg][1]) + (wsum[rg][2] + wsum[rg][3]);
            v /= sum;
            const int i = it * ROWS + rg;
            const size_t row = (size_t)b * NN + i;
            const float rv = res[row * HID + h * DD + dE];
            out[row * HID + h * DD + dE] = fmaxf(v + rv, 0.f);
        }
        if (hf == 0) __syncthreads();                // part consumed before half-2 writes
    }
}

extern "C" void kernel_launch(void* const* d_in, const int* in_sizes, int n_in,
                              void* d_out, int out_size, void* d_ws, size_t ws_size,
                              hipStream_t stream) {
    const float* uf   = (const float*)d_in[0];
    const float* Wsrc = (const float*)d_in[1];
    const float* gsrc = (const float*)d_in[2];
    const float* bsrc = (const float*)d_in[3];
    const float* Wtgt = (const float*)d_in[4];
    const float* gtgt = (const float*)d_in[5];
    const float* btgt = (const float*)d_in[6];
    const float* attn = (const float*)d_in[7];
    const float* Wres = (const float*)d_in[8];
    const float* bres = (const float*)d_in[9];
    float* out = (float*)d_out;

    float* ws   = (float*)d_ws;
    float* Wt   = ws;                       // 128*384   = 49152
    float* Usrc = ws + 49152;               // 4*4*512*32 = 262144
    float* Utgt = Usrc + 262144;
    float* resb = Utgt + 262144;

    pack_w<<<(FIN * NOUT + 255) / 256, 256, 0, stream>>>(Wsrc, Wtgt, Wres, Wt);
    proj_kernel<<<(BB * NN) / MT, NOUT, 0, stream>>>(uf, Wt, gsrc, bsrc, gtgt, btgt,
                                                     bres, Usrc, Utgt, resb);
    attn_kernel<<<BB * HH * (NN / ROWS), 256, 0, stream>>>(Usrc, Utgt, attn, resb, out);
}